// Round 5
// baseline (245.278 us; speedup 1.0000x reference)
//
#include <hip/hip_runtime.h>

typedef float floatx4 __attribute__((ext_vector_type(4)));

#define BB 32
#define HH 56
#define WW 56
#define CC 256
#define TILE_H 8                       // output rows per block
#define HTILES 7                       // 56/8
#define CT 16                          // channels per block (2 groups of 8)
#define CTILES 16                      // 256/16
#define SROWS (TILE_H + 2)             // staged rows incl halo = 10
#define SW (WW + 2)                    // staged width incl halo = 58
#define LDS_F4 (SROWS * SW * (CT/4))   // 2320 float4 = 37.12 KB

__device__ __forceinline__ void load8(const float* __restrict__ p, float v[8]) {
    floatx4 a = *reinterpret_cast<const floatx4*>(p);
    floatx4 b = *reinterpret_cast<const floatx4*>(p + 4);
    v[0]=a[0]; v[1]=a[1]; v[2]=a[2]; v[3]=a[3];
    v[4]=b[0]; v[5]=b[1]; v[6]=b[2]; v[7]=b[3];
}

// LDS stencil tiling (R5). Block = 128 threads = (8 rows x 8 strips x 2 groups).
// Stage x^2 for rows [h0-1, h0+8], w' in [0,58) (zero halo), 16 channels,
// with a 16B-block rotation within each pixel's 16-word LDS line:
//   lds block position p holds source channel-block (p - w') & 3
// so wave-wide b128 reads spread across banks (8 req/bank = b128 floor).
// Compute reads all 9 stencil positions from LDS; only the raw center x
// (needed for the final multiply) comes from global (L2-warm: we just
// staged those lines). XCD pinning: image b -> XCD b&7 (3.2MB image fits
// one XCD's 4MB L2); all 16 ctile-blocks of a row-tile run adjacently.
__global__ __launch_bounds__(128, 2) void dn_kernel(
    const float* __restrict__ x,
    const float* __restrict__ gk_g,
    const float* __restrict__ gs_g,
    const float* __restrict__ beta,
    const float* __restrict__ beta_o,
    const float* __restrict__ gamma_o,
    const int* __restrict__ sdist,
    float* __restrict__ out)
{
    __shared__ float x2s[SROWS * SW * CT];   // 37.12 KB

    const int d = sdist[0];                  // surround_dist (=1)

    // blocks: 32 img x 7 htiles x 16 ctiles = 3584. Pin image to XCD.
    const int xcd = blockIdx.x & 7;
    const int q   = blockIdx.x >> 3;                 // 0..447
    const int b   = xcd + ((q / (HTILES*CTILES)) << 3);
    const int t0  = q % (HTILES*CTILES);
    const int htile = t0 >> 4;                       // /CTILES
    const int ctile = t0 & 15;
    const int h0 = htile * TILE_H;
    const int c0 = ctile * CT;
    const int tid = threadIdx.x;

    const float* xb = x + (size_t)b * HH * WW * CC;

    // ---- stage x^2 tile into LDS (rotated channel blocks) ----
    {
        floatx4* ls = (floatx4*)x2s;
        for (int s = tid; s < LDS_F4; s += 128) {
            const int c4 = s & 3;
            const int wp = (s >> 2) % SW;
            const int r  = s / (SW * 4);
            const int h  = h0 - 1 + r;
            const int w  = wp - 1;
            floatx4 v = {0.f, 0.f, 0.f, 0.f};
            if ((unsigned)h < HH && (unsigned)w < WW) {
                const int src4 = (c4 - wp) & 3;      // unrotate
                const floatx4* gp = (const floatx4*)(xb + (size_t)(h*WW + w)*CC + c0) + src4;
                floatx4 u = *gp;
                v = u * u;
            }
            ls[s] = v;   // f4 index = (r*SW + wp)*4 + c4
        }
    }

    // ---- per-thread weights (8 output channels) ----
    const int row   = tid >> 4;        // 0..7
    const int strip = (tid >> 1) & 7;  // 0..7
    const int gi    = tid & 1;
    const int cb    = c0 + gi * 8;     // global channel base (group-aligned)
    const int o4a   = gi * 2, o4b = gi * 2 + 1;   // original 16B-block ids

    float gk[8][8];
#pragma unroll
    for (int i = 0; i < 8; ++i) load8(gk_g + i*CC + cb, gk[i]);

    const int tap_kh[8] = {0,0,0,1,1,2,2,2};
    const int tap_kw[8] = {0,1,2,0,2,0,1,2};
    float gs[8][8];
#pragma unroll
    for (int t = 0; t < 8; ++t)
        load8(gs_g + (tap_kh[t]*3 + tap_kw[t])*CC + cb, gs[t]);

    float betav[8], gov[8], bov[8];
    load8(beta    + cb, betav);
    load8(gamma_o + cb, gov);
    load8(beta_o  + cb, bov);
#pragma unroll
    for (int o = 0; o < 8; ++o) betav[o] += 1e-6f;   // BETA_MIN

    __syncthreads();

    const int h = h0 + row;
    const float* xrow = xb + (size_t)(h * WW) * CC;
    float*       orow = out + ((size_t)(b * HH + h) * WW) * CC;
    const floatx4* ls = (const floatx4*)x2s;

    for (int j = 0; j < 7; ++j) {
        const int w  = strip * 7 + j;
        const int wp = w + 1;

        float cx[8];
        load8(xrow + w*CC + cb, cx);     // raw center, L2-warm

        float acc[8];
#pragma unroll
        for (int o = 0; o < 8; ++o) acc[o] = betav[o];

        int t = 0;
#pragma unroll
        for (int dr = -1; dr <= 1; ++dr) {
#pragma unroll
            for (int dw = -1; dw <= 1; ++dw) {
                const int rt = row + 1 + dr * d;
                const int wt = wp + dw * d;
                const int fb = (rt * SW + wt) * (CT/4);
                const floatx4 A = ls[fb + ((o4a + wt) & 3)];
                const floatx4 B = ls[fb + ((o4b + wt) & 3)];
                if (dr == 0 && dw == 0) {
                    // Pk: 8x8 group mix of center x^2
#pragma unroll
                    for (int o = 0; o < 8; ++o)
                        acc[o] += A[0]*gk[0][o] + A[1]*gk[1][o]
                                + A[2]*gk[2][o] + A[3]*gk[3][o]
                                + B[0]*gk[4][o] + B[1]*gk[5][o]
                                + B[2]*gk[6][o] + B[3]*gk[7][o];
                } else {
                    // Ps tap
#pragma unroll
                    for (int o = 0; o < 4; ++o) acc[o]     += A[o] * gs[t][o];
#pragma unroll
                    for (int o = 0; o < 4; ++o) acc[4 + o] += B[o] * gs[t][4 + o];
                    ++t;   // folds at compile time (dr/dw unrolled)
                }
            }
        }

        floatx4 r0, r1;
#pragma unroll
        for (int o = 0; o < 4; ++o) {
            r0[o] = cx[o]     * __builtin_amdgcn_rsqf(acc[o])     * gov[o]     + bov[o];
            r1[o] = cx[4 + o] * __builtin_amdgcn_rsqf(acc[4 + o]) * gov[4 + o] + bov[4 + o];
        }
        floatx4* op = (floatx4*)(orow + w*CC + cb);
        op[0] = r0;
        op[1] = r1;
    }
}

extern "C" void kernel_launch(void* const* d_in, const int* in_sizes, int n_in,
                              void* d_out, int out_size, void* d_ws, size_t ws_size,
                              hipStream_t stream) {
    const float* x       = (const float*)d_in[0];
    const float* gamma_k = (const float*)d_in[1];
    const float* gamma_s = (const float*)d_in[2];
    const float* beta    = (const float*)d_in[3];
    const float* beta_o  = (const float*)d_in[4];
    const float* gamma_o = (const float*)d_in[5];
    const int*   sdist   = (const int*)d_in[6];
    float* out = (float*)d_out;

    const int blocks = BB * HTILES * CTILES;   // 3584
    dn_kernel<<<blocks, 128, 0, stream>>>(x, gamma_k, gamma_s, beta,
                                          beta_o, gamma_o, sdist, out);
}

// Round 6
// 241.155 us; speedup vs baseline: 1.0171x; 1.0171x over previous
//
#include <hip/hip_runtime.h>

typedef float floatx4 __attribute__((ext_vector_type(4)));

#define BB 32
#define HH 56
#define WW 56
#define CC 256
#define PSTRIP 4
#define WSTRIPS 14                      // 56/4
#define HTILE 4                         // rows per block (4 waves, 1 row each)
#define HTILES 14                       // 56/4
#define BLOCKS_PER_IMG (HTILES * WSTRIPS)  // 196

// R6: lane = channel-QUAD (4 ch), wave = one full pixel (64*4 = 256 ch).
// Per-thread weights halve vs R4/R5 (gk 32 + gs 32 regs instead of 128),
// freeing VGPRs so all 9 per-pixel tap/center loads stay independent and
// in flight (the R4/R5 stall was serialized load->wait chains under
// register pressure; everything sat <30% busy = latency-bound).
// Every tap load: lane L reads x[pix, 4L..4L+3] -> one coalesced 1KB
// dwordx4 per wave. Tap bounds checks are wave-uniform (h,w uniform in
// wave) -> s_cbranch, zero divergence.
// Block = 4 rows x one 4-wide strip (vertical tap reuse in L1).
// XCD pinning: image b -> XCD b&7 (3.2MB image fits 4MB XCD L2);
// NT stores keep the write stream from evicting the x tile (R4-proven:
// FETCH 50MB). launch_bounds(256,3) caps VGPR at 168 -- above the ~150
// estimate so R3-style scratch spills cannot happen.
__global__ __launch_bounds__(256, 3) void dn_kernel(
    const float* __restrict__ x,
    const float* __restrict__ gk_g,
    const float* __restrict__ gs_g,
    const float* __restrict__ beta,
    const float* __restrict__ beta_o,
    const float* __restrict__ gamma_o,
    const int* __restrict__ sdist,
    float* __restrict__ out)
{
    const int d    = sdist[0];                 // surround_dist (=1)
    const int xcd  = blockIdx.x & 7;
    const int q    = blockIdx.x >> 3;          // 0..783
    const int b    = xcd + ((q / BLOCKS_PER_IMG) << 3);
    const int t0   = q % BLOCKS_PER_IMG;
    const int h    = (t0 / WSTRIPS) * HTILE + (threadIdx.x >> 6);
    const int w0   = (t0 % WSTRIPS) * PSTRIP;
    const int lane = threadIdx.x & 63;
    const int c0   = lane << 2;                // own channel quad
    const int cg   = c0 & ~7;                  // group base (8 ch)

    const int tap_kh[8] = {0,0,0,1,1,2,2,2};
    const int tap_kw[8] = {0,1,2,0,2,0,1,2};

    // gk[i][o] = gamma_k weight: input i of group, output channel c0+o
    floatx4 gk[8];
#pragma unroll
    for (int i = 0; i < 8; ++i)
        gk[i] = *reinterpret_cast<const floatx4*>(gk_g + i*CC + c0);

    floatx4 gsw[8];
#pragma unroll
    for (int tt = 0; tt < 8; ++tt)
        gsw[tt] = *reinterpret_cast<const floatx4*>(
                      gs_g + (tap_kh[tt]*3 + tap_kw[tt])*CC + c0);

    floatx4 betav = *reinterpret_cast<const floatx4*>(beta + c0);
    betav += 1e-6f;                            // BETA_MIN
    const floatx4 gov = *reinterpret_cast<const floatx4*>(gamma_o + c0);
    const floatx4 bov = *reinterpret_cast<const floatx4*>(beta_o  + c0);

    const float* xb   = x + (size_t)b * HH * WW * CC;
    const float* xrow = xb + (size_t)h * WW * CC;
    float*       orow = out + ((size_t)(b*HH + h) * WW) * CC;

#pragma unroll
    for (int j = 0; j < PSTRIP; ++j) {
        const int w = w0 + j;
        const float* cp = xrow + w*CC;

        // center: full 8-ch group (lane pairs duplicate-read the same 32B)
        floatx4 cxa = *reinterpret_cast<const floatx4*>(cp + cg);
        floatx4 cxb = *reinterpret_cast<const floatx4*>(cp + cg + 4);

        // 8 neighbor taps, own quad only; wave-uniform predication
        floatx4 tp[8];
#pragma unroll
        for (int tt = 0; tt < 8; ++tt) {
            const int hh = h + (tap_kh[tt]-1)*d;
            const int w2 = w + (tap_kw[tt]-1)*d;
            floatx4 v = {0.f, 0.f, 0.f, 0.f};
            if ((unsigned)hh < HH && (unsigned)w2 < WW)
                v = *reinterpret_cast<const floatx4*>(
                        xb + (size_t)(hh*WW + w2)*CC + c0);
            tp[tt] = v;
        }

        // Pk: 8 group inputs x own 4 outputs
        floatx4 acc = betav;
        const floatx4 sqa = cxa*cxa, sqb = cxb*cxb;
#pragma unroll
        for (int i = 0; i < 4; ++i) acc += sqa[i] * gk[i];
#pragma unroll
        for (int i = 0; i < 4; ++i) acc += sqb[i] * gk[4+i];
        // Ps: 8 depthwise taps on own quad
#pragma unroll
        for (int tt = 0; tt < 8; ++tt) acc += (tp[tt]*tp[tt]) * gsw[tt];

        const floatx4 cxo = (lane & 1) ? cxb : cxa;   // raw own quad
        floatx4 res;
#pragma unroll
        for (int o = 0; o < 4; ++o)
            res[o] = cxo[o] * __builtin_amdgcn_rsqf(acc[o]) * gov[o] + bov[o];

        __builtin_nontemporal_store(res,
            reinterpret_cast<floatx4*>(orow + w*CC + c0));
    }
}

extern "C" void kernel_launch(void* const* d_in, const int* in_sizes, int n_in,
                              void* d_out, int out_size, void* d_ws, size_t ws_size,
                              hipStream_t stream) {
    const float* x       = (const float*)d_in[0];
    const float* gamma_k = (const float*)d_in[1];
    const float* gamma_s = (const float*)d_in[2];
    const float* beta    = (const float*)d_in[3];
    const float* beta_o  = (const float*)d_in[4];
    const float* gamma_o = (const float*)d_in[5];
    const int*   sdist   = (const int*)d_in[6];
    float* out = (float*)d_out;

    const int blocks = BB * BLOCKS_PER_IMG;   // 6272
    dn_kernel<<<blocks, 256, 0, stream>>>(x, gamma_k, gamma_s, beta,
                                          beta_o, gamma_o, sdist, out);
}